// Round 1
// baseline (252.806 us; speedup 1.0000x reference)
//
#include <hip/hip_runtime.h>

#define N 8192
#define D 64
#define JSPLIT 16
#define JSTEPS (N / 64 / JSPLIT)   // 8 J-tiles of 64 cols per block

typedef unsigned short ushort_t;
typedef __attribute__((ext_vector_type(8))) short bf16x8;
typedef __attribute__((ext_vector_type(4))) float f32x4;

__device__ inline ushort_t f32_to_bf16(float f) {
    union { float f; unsigned u; } c; c.f = f;
    unsigned r = (c.u + 0x7FFFu + ((c.u >> 16) & 1u)) >> 16;
    return (ushort_t)r;
}

// ---------------- kernel 1: L2-normalize rows, emit bf16 ----------------
// zn layout: [0..N) rows = normalized z_mp, [N..2N) rows = normalized z_sc
__global__ void normalize_kernel(const float* __restrict__ z_mp,
                                 const float* __restrict__ z_sc,
                                 ushort_t* __restrict__ zn) {
    int lane = threadIdx.x & 63;
    int row  = blockIdx.x * 4 + (threadIdx.x >> 6);
    const float* src = (row < N) ? z_mp : z_sc;
    int srow = row & (N - 1);
    float x = src[srow * D + lane];
    float s = x * x;
    #pragma unroll
    for (int m = 32; m; m >>= 1) s += __shfl_xor(s, m, 64);
    float n = sqrtf(s);
    float scale = 1.0f / fmaxf(n, 1e-12f);
    zn[row * D + lane] = f32_to_bf16(x * scale);
}

// ---------------- kernel 2: tiled 4-pair similarity + row accumulation --
// accum layout: accum[t*2*N + i] = rowsum(term t), accum[t*2*N + N + i] = possum
__global__ __launch_bounds__(256, 2) void contrast_main(
        const ushort_t* __restrict__ zn,
        const float* __restrict__ pos,
        float* __restrict__ accum) {
    int lane   = threadIdx.x & 63;
    int w      = threadIdx.x >> 6;     // wave 0..3
    int a      = w >> 1, b = w & 1;    // A,B source: 0=mp, 1=sc
    // term: (0,0)->mp2mp(2), (0,1)->mp2sc(0), (1,0)->sc2mp(1), (1,1)->sc2sc(3)
    int term   = (a == 0) ? (b == 0 ? 2 : 0) : (b == 0 ? 1 : 3);
    int rquart = lane >> 4;            // 0..3
    int lcol   = lane & 15;            // 0..15

    const ushort_t* Az = zn + a * (N * D);
    const ushort_t* Bz = zn + b * (N * D);

    int I0 = blockIdx.x * 64;
    int J0 = blockIdx.y * (N / JSPLIT);

    // A fragments: row = I0 + 16r + (lane&15), k = s*32 + (lane>>4)*8 .. +8
    bf16x8 af[4][2];
    #pragma unroll
    for (int r = 0; r < 4; ++r)
        #pragma unroll
        for (int s = 0; s < 2; ++s)
            af[r][s] = *(const bf16x8*)(Az + (I0 + 16 * r + lcol) * D + s * 32 + rquart * 8);

    float rs_acc[4][4];   // [r][e] per-row partial rowsum
    float ps_acc[4][4];   // [r][e] per-row partial possum
    #pragma unroll
    for (int r = 0; r < 4; ++r)
        #pragma unroll
        for (int e = 0; e < 4; ++e) { rs_acc[r][e] = 0.0f; ps_acc[r][e] = 0.0f; }

    for (int jj = 0; jj < JSTEPS; ++jj) {
        int Jc = J0 + jj * 64;

        // B fragments: col(row j) = Jc + 16c + (lane&15), k = s*32 + (lane>>4)*8
        bf16x8 bf[4][2];
        #pragma unroll
        for (int c = 0; c < 4; ++c)
            #pragma unroll
            for (int s = 0; s < 2; ++s)
                bf[c][s] = *(const bf16x8*)(Bz + (Jc + 16 * c + lcol) * D + s * 32 + rquart * 8);

        f32x4 acc[4][4];
        #pragma unroll
        for (int r = 0; r < 4; ++r)
            #pragma unroll
            for (int c = 0; c < 4; ++c)
                acc[r][c] = (f32x4){0.f, 0.f, 0.f, 0.f};

        #pragma unroll
        for (int s = 0; s < 2; ++s)
            #pragma unroll
            for (int r = 0; r < 4; ++r)
                #pragma unroll
                for (int c = 0; c < 4; ++c)
                    acc[r][c] = __builtin_amdgcn_mfma_f32_16x16x32_bf16(
                        af[r][s], bf[c][s], acc[r][c], 0, 0, 0);

        // epilogue: exp(2*cos), pair with pos[i][j], accumulate per-row
        long rowOff = (long)(I0 + rquart * 4) * N + (Jc + lcol);
        #pragma unroll
        for (int r = 0; r < 4; ++r) {
            #pragma unroll
            for (int e = 0; e < 4; ++e) {
                const float* pp = pos + rowOff + (long)(16 * r + e) * N;
                #pragma unroll
                for (int c = 0; c < 4; ++c) {
                    float eV = __expf(2.0f * acc[r][c][e]);
                    float pv = pp[16 * c];
                    rs_acc[r][e] += eV;
                    ps_acc[r][e] += eV * pv;
                }
            }
        }
    }

    // butterfly-reduce across the 16 lanes sharing each row (bits 0..3 of lane)
    #pragma unroll
    for (int r = 0; r < 4; ++r)
        #pragma unroll
        for (int e = 0; e < 4; ++e) {
            float rs = rs_acc[r][e], ps = ps_acc[r][e];
            #pragma unroll
            for (int m = 1; m < 16; m <<= 1) {
                rs += __shfl_xor(rs, m, 64);
                ps += __shfl_xor(ps, m, 64);
            }
            rs_acc[r][e] = rs; ps_acc[r][e] = ps;
        }

    if (lcol == 0) {
        #pragma unroll
        for (int r = 0; r < 4; ++r)
            #pragma unroll
            for (int e = 0; e < 4; ++e) {
                int gi = I0 + 16 * r + rquart * 4 + e;
                atomicAdd(&accum[term * 2 * N + gi],     rs_acc[r][e]);
                atomicAdd(&accum[term * 2 * N + N + gi], ps_acc[r][e]);
            }
    }
}

// ---------------- kernel 3: final loss reduction ------------------------
__global__ void finalize_kernel(const float* __restrict__ accum,
                                float* __restrict__ out) {
    __shared__ float red[256];
    float local = 0.0f;
    for (int i = threadIdx.x; i < N; i += 256) {
        float s = 0.0f;
        #pragma unroll
        for (int t = 0; t < 4; ++t) {
            float rs = accum[t * 2 * N + i];
            float ps = accum[t * 2 * N + N + i];
            s += logf(ps / (rs + 1e-8f));
        }
        local += s;
    }
    red[threadIdx.x] = local;
    __syncthreads();
    for (int m = 128; m; m >>= 1) {
        if (threadIdx.x < m) red[threadIdx.x] += red[threadIdx.x + m];
        __syncthreads();
    }
    if (threadIdx.x == 0) out[0] = -red[0] / (float)N;
}

extern "C" void kernel_launch(void* const* d_in, const int* in_sizes, int n_in,
                              void* d_out, int out_size, void* d_ws, size_t ws_size,
                              hipStream_t stream) {
    const float* z_mp = (const float*)d_in[0];
    const float* z_sc = (const float*)d_in[1];
    const float* pos  = (const float*)d_in[2];
    float* out = (float*)d_out;

    ushort_t* zn = (ushort_t*)d_ws;                                 // 2*N*D*2 = 2 MB
    float* accum = (float*)((char*)d_ws + (size_t)2 * N * D * sizeof(ushort_t));  // 256 KB

    hipMemsetAsync(accum, 0, (size_t)4 * 2 * N * sizeof(float), stream);
    normalize_kernel<<<(2 * N) / 4, 256, 0, stream>>>(z_mp, z_sc, zn);
    dim3 grid(N / 64, JSPLIT);
    contrast_main<<<grid, 256, 0, stream>>>(zn, pos, accum);
    finalize_kernel<<<1, 256, 0, stream>>>(accum, out);
}

// Round 2
// 169.379 us; speedup vs baseline: 1.4925x; 1.4925x over previous
//
#include <hip/hip_runtime.h>

#define N 8192
#define D 64
#define JSPLIT 16
#define JSTEPS (N / 64 / JSPLIT)   // 8 J-tiles of 64 cols per block

typedef unsigned short ushort_t;
typedef __attribute__((ext_vector_type(8))) short bf16x8;
typedef __attribute__((ext_vector_type(4))) float f32x4;

#define TWO_OVER_LN2 2.885390081777927f   // exp(2x) == exp2(x * 2/ln2)

__device__ inline ushort_t f32_to_bf16(float f) {
    union { float f; unsigned u; } c; c.f = f;
    unsigned r = (c.u + 0x7FFFu + ((c.u >> 16) & 1u)) >> 16;
    return (ushort_t)r;
}

// ---------------- kernel 1: L2-normalize rows, emit bf16 ----------------
__global__ void normalize_kernel(const float* __restrict__ z_mp,
                                 const float* __restrict__ z_sc,
                                 ushort_t* __restrict__ zn) {
    int lane = threadIdx.x & 63;
    int row  = blockIdx.x * 4 + (threadIdx.x >> 6);
    const float* src = (row < N) ? z_mp : z_sc;
    int srow = row & (N - 1);
    float x = src[srow * D + lane];
    float s = x * x;
    #pragma unroll
    for (int m = 32; m; m >>= 1) s += __shfl_xor(s, m, 64);
    float n = sqrtf(s);
    float scale = 1.0f / fmaxf(n, 1e-12f);
    zn[row * D + lane] = f32_to_bf16(x * scale);
}

// ---------------- kernel 2: tiled 4-pair similarity + row accumulation --
// Column permutation trick: B-fragment c is loaded from row (Jc + 4*lcol + c),
// so acc[r][c][e] corresponds to global column Jc + 4*lcol + c. A lane's 4
// columns are CONTIGUOUS -> pos reads become coalesced f32x4 loads.
__global__ __launch_bounds__(256, 3) void contrast_main(
        const ushort_t* __restrict__ zn,
        const float* __restrict__ pos,
        float* __restrict__ accum) {
    int lane   = threadIdx.x & 63;
    int w      = threadIdx.x >> 6;     // wave 0..3
    int a      = w >> 1, b = w & 1;    // A,B source: 0=mp, 1=sc
    // term: (0,0)->mp2mp(2), (0,1)->mp2sc(0), (1,0)->sc2mp(1), (1,1)->sc2sc(3)
    int term   = (a == 0) ? (b == 0 ? 2 : 0) : (b == 0 ? 1 : 3);
    int rquart = lane >> 4;            // 0..3
    int lcol   = lane & 15;            // 0..15

    const ushort_t* Az = zn + a * (N * D);
    const ushort_t* Bz = zn + b * (N * D);

    int I0 = blockIdx.x * 64;
    int J0 = blockIdx.y * (N / JSPLIT);

    // A fragments: row = I0 + 16r + lcol, k = s*32 + rquart*8 .. +8
    bf16x8 af[4][2];
    #pragma unroll
    for (int r = 0; r < 4; ++r)
        #pragma unroll
        for (int s = 0; s < 2; ++s)
            af[r][s] = *(const bf16x8*)(Az + (I0 + 16 * r + lcol) * D + s * 32 + rquart * 8);

    float rs_acc[4][4];   // [r][e] per-row partial rowsum
    float ps_acc[4][4];   // [r][e] per-row partial possum
    #pragma unroll
    for (int r = 0; r < 4; ++r)
        #pragma unroll
        for (int e = 0; e < 4; ++e) { rs_acc[r][e] = 0.0f; ps_acc[r][e] = 0.0f; }

    for (int jj = 0; jj < JSTEPS; ++jj) {
        int Jc = J0 + jj * 64;

        // B fragments, PERMUTED: fragment c <- row (Jc + 4*lcol + c)
        bf16x8 bf[4][2];
        #pragma unroll
        for (int c = 0; c < 4; ++c)
            #pragma unroll
            for (int s = 0; s < 2; ++s)
                bf[c][s] = *(const bf16x8*)(Bz + (Jc + 4 * lcol + c) * D + s * 32 + rquart * 8);

        // base of this lane's contiguous 4-column pos quad, at row (I0 + rquart*4)
        const float* prow = pos + (long)(I0 + rquart * 4) * N + (Jc + 4 * lcol);

        // software-pipelined over r: prefetch pv for r+1 during r's MFMA+epilogue
        f32x4 pv[2][4];
        #pragma unroll
        for (int e = 0; e < 4; ++e)
            pv[0][e] = *(const f32x4*)(prow + (long)e * N);

        #pragma unroll
        for (int r = 0; r < 4; ++r) {
            if (r < 3) {
                #pragma unroll
                for (int e = 0; e < 4; ++e)
                    pv[(r + 1) & 1][e] = *(const f32x4*)(prow + (long)(16 * (r + 1) + e) * N);
            }

            f32x4 acc[4];
            #pragma unroll
            for (int c = 0; c < 4; ++c) acc[c] = (f32x4){0.f, 0.f, 0.f, 0.f};
            #pragma unroll
            for (int s = 0; s < 2; ++s)
                #pragma unroll
                for (int c = 0; c < 4; ++c)
                    acc[c] = __builtin_amdgcn_mfma_f32_16x16x32_bf16(
                        af[r][s], bf[c][s], acc[c], 0, 0, 0);

            #pragma unroll
            for (int e = 0; e < 4; ++e) {
                f32x4 p = pv[r & 1][e];
                float rs = rs_acc[r][e], ps = ps_acc[r][e];
                #pragma unroll
                for (int c = 0; c < 4; ++c) {
                    float eV = exp2f(acc[c][e] * TWO_OVER_LN2);
                    rs += eV;
                    ps = fmaf(eV, p[c], ps);
                }
                rs_acc[r][e] = rs; ps_acc[r][e] = ps;
            }
        }
    }

    // butterfly-reduce across the 16 lanes sharing each row (bits 0..3 of lane)
    #pragma unroll
    for (int r = 0; r < 4; ++r)
        #pragma unroll
        for (int e = 0; e < 4; ++e) {
            float rs = rs_acc[r][e], ps = ps_acc[r][e];
            #pragma unroll
            for (int m = 1; m < 16; m <<= 1) {
                rs += __shfl_xor(rs, m, 64);
                ps += __shfl_xor(ps, m, 64);
            }
            rs_acc[r][e] = rs; ps_acc[r][e] = ps;
        }

    if (lcol == 0) {
        #pragma unroll
        for (int r = 0; r < 4; ++r)
            #pragma unroll
            for (int e = 0; e < 4; ++e) {
                int gi = I0 + 16 * r + rquart * 4 + e;
                atomicAdd(&accum[term * 2 * N + gi],     rs_acc[r][e]);
                atomicAdd(&accum[term * 2 * N + N + gi], ps_acc[r][e]);
            }
    }
}

// ---------------- kernel 3: final loss reduction ------------------------
__global__ void finalize_kernel(const float* __restrict__ accum,
                                float* __restrict__ out) {
    __shared__ float red[256];
    float local = 0.0f;
    for (int i = threadIdx.x; i < N; i += 256) {
        float s = 0.0f;
        #pragma unroll
        for (int t = 0; t < 4; ++t) {
            float rs = accum[t * 2 * N + i];
            float ps = accum[t * 2 * N + N + i];
            s += logf(ps / (rs + 1e-8f));
        }
        local += s;
    }
    red[threadIdx.x] = local;
    __syncthreads();
    for (int m = 128; m; m >>= 1) {
        if (threadIdx.x < m) red[threadIdx.x] += red[threadIdx.x + m];
        __syncthreads();
    }
    if (threadIdx.x == 0) out[0] = -red[0] / (float)N;
}

extern "C" void kernel_launch(void* const* d_in, const int* in_sizes, int n_in,
                              void* d_out, int out_size, void* d_ws, size_t ws_size,
                              hipStream_t stream) {
    const float* z_mp = (const float*)d_in[0];
    const float* z_sc = (const float*)d_in[1];
    const float* pos  = (const float*)d_in[2];
    float* out = (float*)d_out;

    ushort_t* zn = (ushort_t*)d_ws;                                 // 2*N*D*2 = 2 MB
    float* accum = (float*)((char*)d_ws + (size_t)2 * N * D * sizeof(ushort_t));  // 256 KB

    hipMemsetAsync(accum, 0, (size_t)4 * 2 * N * sizeof(float), stream);
    normalize_kernel<<<(2 * N) / 4, 256, 0, stream>>>(z_mp, z_sc, zn);
    dim3 grid(N / 64, JSPLIT);
    contrast_main<<<grid, 256, 0, stream>>>(zn, pos, accum);
    finalize_kernel<<<1, 256, 0, stream>>>(accum, out);
}